// Round 8
// baseline (246.324 us; speedup 1.0000x reference)
//
#include <hip/hip_runtime.h>
#include <hip/hip_bf16.h>
#include <math.h>

#define BB   16      // batch
#define NC   1024    // candidates per query row
#define QL   32      // query tokens
#define HD   128     // embed dim
#define DLN  64      // doc tokens per doc
#define RK   128     // rescore set size per row (pow2, >= k=100 with margin)
#define NPW  2       // candidates per wave in the screen kernel

typedef __attribute__((ext_vector_type(8))) short bf16x8;  // 8 bf16 (4 VGPRs)
typedef __attribute__((ext_vector_type(4))) float f32x4;   // MFMA accumulator

// ---------------------------------------------------------------------------
// K1: fused qprep + gather/sort/dedup. Block b also converts q row-block b
// (QL*HD = 4096 elems) to bf16 for the MFMA screen.
// ---------------------------------------------------------------------------
__global__ __launch_bounds__(1024) void k_gather_sort_dedup(
    const int* __restrict__ topk, const int* __restrict__ emb2pid,
    const float* __restrict__ q, unsigned short* __restrict__ qhi,
    int n_emb, int n_docs, int* __restrict__ pids_out)
{
    const int b = blockIdx.x;
    const int t = threadIdx.x;
    __shared__ int s[NC];

    // qprep: 4 elements per thread.
#pragma unroll
    for (int j = 0; j < 4; ++j) {
        int i = b * (QL * HD) + t * 4 + j;
        float v = q[i];
        __hip_bfloat16 h = __float2bfloat16(v);
        qhi[i] = *reinterpret_cast<unsigned short*>(&h);
    }

    int idx = topk[b * NC + t];
    int pid = (idx >= 0 && idx < n_emb) ? emb2pid[idx] : -1;
    if (pid < 0 || pid >= n_docs) pid = -1;
    s[t] = pid;
    __syncthreads();

    for (int k2 = 2; k2 <= NC; k2 <<= 1) {
        for (int j = k2 >> 1; j > 0; j >>= 1) {
            int ixj = t ^ j;
            if (ixj > t) {
                int a = s[t], c = s[ixj];
                bool desc = ((t & k2) == 0);
                if (desc ? (a < c) : (a > c)) { s[t] = c; s[ixj] = a; }
            }
            __syncthreads();
        }
    }
    int v = s[t];
    pids_out[b * NC + t] = (t > 0 && v == s[t - 1]) ? -1 : v;
}

// ---------------------------------------------------------------------------
// Round 8 f32 to bf16 (RNE) -> one bf16x8 fragment.
// ---------------------------------------------------------------------------
__device__ __forceinline__ bf16x8 cvt8(float4 a, float4 c)
{
    float v[8] = {a.x, a.y, a.z, a.w, c.x, c.y, c.z, c.w};
    bf16x8 r;
#pragma unroll
    for (int j = 0; j < 8; ++j) {
        __hip_bfloat16 h = __float2bfloat16(v[j]);
        r[j] = *reinterpret_cast<short*>(&h);
    }
    return r;
}

// ---------------------------------------------------------------------------
// K2: MFMA screening (R7 version, kept: +22us win). One wave per NPW cands;
// register-direct doc loads, no LDS/barriers; launch_bounds(256,4) caps VGPR
// at 128 for 4 waves/SIMD.
// ---------------------------------------------------------------------------
__global__ __launch_bounds__(256, 4) void k_screen_mfma(
    const unsigned short* __restrict__ qhi,  // [BB][QL][HD] bf16(q)
    const float* __restrict__ vecs,          // [n_docs][DLN][HD] f32
    const int* __restrict__ pids,            // [BB][NC]
    float* __restrict__ scores)              // [BB][NC]
{
    const int lane = threadIdx.x & 63;
    const int wv   = threadIdx.x >> 6;              // 0..3
    const int bk   = blockIdx.x;
    const int BPR  = NC / (4 * NPW);                // blocks per batch row
    const int b    = bk / BPR;
    const int nb   = (bk % BPR) * (4 * NPW) + wv * NPW;

    const int r16 = lane & 15;
    const int kb  = lane >> 4;

    bf16x8 qf[2][4];
#pragma unroll
    for (int m = 0; m < 2; ++m)
#pragma unroll
        for (int ks = 0; ks < 4; ++ks) {
            int off = ((b * QL + m * 16 + r16) * HD + ks * 32 + kb * 8);
            qf[m][ks] = *(const bf16x8*)(qhi + off);
        }

    for (int nn = 0; nn < NPW; ++nn) {
        const int n = nb + nn;
        const int pid = pids[b * NC + n];
        if (pid < 0) {
            if (lane == 0) scores[b * NC + n] = -__builtin_inff();
            continue;
        }
        const float* dbase = vecs + (size_t)pid * (DLN * HD);

        f32x4 acc[2][4] = {};
#pragma unroll
        for (int ks = 0; ks < 4; ++ks) {
#pragma unroll
            for (int nt = 0; nt < 4; ++nt) {
                const float* p = dbase + (nt * 16 + r16) * HD + ks * 32 + kb * 8;
                float4 x0 = *(const float4*)p;
                float4 x1 = *(const float4*)(p + 4);
                bf16x8 bh = cvt8(x0, x1);
#pragma unroll
                for (int m = 0; m < 2; ++m)
                    acc[m][nt] = __builtin_amdgcn_mfma_f32_16x16x32_bf16(
                        qf[m][ks], bh, acc[m][nt], 0, 0, 0);
            }
        }

        float s = 0.f;
#pragma unroll
        for (int m = 0; m < 2; ++m) {
#pragma unroll
            for (int r = 0; r < 4; ++r) {
                float x = fmaxf(fmaxf(acc[m][0][r], acc[m][1][r]),
                                fmaxf(acc[m][2][r], acc[m][3][r]));
                x = fmaxf(x, __shfl_xor(x, 1));
                x = fmaxf(x, __shfl_xor(x, 2));
                x = fmaxf(x, __shfl_xor(x, 4));
                x = fmaxf(x, __shfl_xor(x, 8));
                s += x;
            }
        }
        s += __shfl_xor(s, 16);
        s += __shfl_xor(s, 32);
        if (lane == 0) scores[b * NC + n] = s * (1.0f / 32.0f);
    }
}

// ---------------------------------------------------------------------------
// K3a: per-row full bitonic sort of (f32 score desc, idx asc); keep top RK.
// ---------------------------------------------------------------------------
__global__ __launch_bounds__(1024) void k_select(
    const float* __restrict__ scores, int* __restrict__ sel)
{
    const int b = blockIdx.x;
    const int t = threadIdx.x;
    __shared__ float ss[NC];
    __shared__ int   si[NC];

    ss[t] = scores[b * NC + t];
    si[t] = t;
    __syncthreads();

    for (int k2 = 2; k2 <= NC; k2 <<= 1) {
        for (int j = k2 >> 1; j > 0; j >>= 1) {
            int ixj = t ^ j;
            if (ixj > t) {
                float as = ss[t], bs = ss[ixj];
                int   ai = si[t], bi = si[ixj];
                bool a_first = (as > bs) || (as == bs && ai < bi);
                bool desc = ((t & k2) == 0);
                if (desc ? !a_first : a_first) { ss[t] = bs; si[t] = bi; ss[ixj] = as; si[ixj] = ai; }
            }
            __syncthreads();
        }
    }
    if (t < RK) sel[b * RK + t] = si[t];
}

// ---------------------------------------------------------------------------
// K3b: chunked exact f64 rescore. Each block handles 32 doc rows (half a doc)
// of one selected candidate: 18 KB LDS -> 8 blocks/CU (full occupancy), 2x
// parallelism vs the monolithic version. Per-(q,d) dot keeps the exact R1
// expression/order; per-q partial MAX over this chunk's 32 rows is exact
// under any grouping. Writes pmax[b][r][chunk][32].
// ---------------------------------------------------------------------------
#define CPAD (HD + 4)

__global__ __launch_bounds__(256) void k_rescore_chunk(
    const float* __restrict__ q,     // [BB][QL][HD]
    const float* __restrict__ vecs,  // [n_docs][DLN][HD]
    const int* __restrict__ pids,    // [BB][NC]
    const int* __restrict__ sel,     // [BB][RK]
    double* __restrict__ pmax)       // [BB][RK][2][QL]
{
    const int r = blockIdx.x, c = blockIdx.y, b = blockIdx.z;
    const int t = threadIdx.x;
    const int n = sel[b * RK + r];
    const int pid = pids[b * NC + n];
    double* out = pmax + (((size_t)(b * RK + r)) * 2 + c) * QL;
    if (pid < 0) {
        if (t < QL) out[t] = -__builtin_inf();
        return;
    }

    __shared__ float sdoc[32][CPAD];
    __shared__ double red[4][16][2];

    {
        const float4* src = (const float4*)(vecs + ((size_t)pid * DLN + c * 32) * HD);
        for (int i = t; i < 32 * HD / 4; i += 256) {
            float4 v = src[i];
            int d = i >> 5, h4 = (i & 31) << 2;
            *(float4*)&sdoc[d][h4] = v;
        }
    }
    __syncthreads();

    const int tq = t & 15;                   // q rows {2tq, 2tq+1}
    const int td = t >> 4;                   // d rows {2td, 2td+1} in chunk
    const float* qb = q + ((size_t)b * QL + tq * 2) * HD;

    const int d0 = td * 2;
    double a00 = 0.0, a01 = 0.0, a10 = 0.0, a11 = 0.0;
    for (int h = 0; h < HD; h += 4) {
        float4 qa = *(const float4*)(qb + h);
        float4 qc = *(const float4*)(qb + HD + h);
        float4 b0 = *(const float4*)&sdoc[d0][h];
        float4 b1 = *(const float4*)&sdoc[d0 + 1][h];
        a00 += (double)qa.x * b0.x + (double)qa.y * b0.y
             + (double)qa.z * b0.z + (double)qa.w * b0.w;
        a01 += (double)qa.x * b1.x + (double)qa.y * b1.y
             + (double)qa.z * b1.z + (double)qa.w * b1.w;
        a10 += (double)qc.x * b0.x + (double)qc.y * b0.y
             + (double)qc.z * b0.z + (double)qc.w * b0.w;
        a11 += (double)qc.x * b1.x + (double)qc.y * b1.y
             + (double)qc.z * b1.z + (double)qc.w * b1.w;
    }
    double m0 = fmax(a00, a01);
    double m1 = fmax(a10, a11);

    // Max across the wave's 4 td groups (lanes l, l^16, l^32, l^48 share tq).
    m0 = fmax(m0, __shfl_xor(m0, 16)); m1 = fmax(m1, __shfl_xor(m1, 16));
    m0 = fmax(m0, __shfl_xor(m0, 32)); m1 = fmax(m1, __shfl_xor(m1, 32));

    const int wave = t >> 6;
    if ((t & 63) < 16) { red[wave][tq][0] = m0; red[wave][tq][1] = m1; }
    __syncthreads();

    if (t < 32) {
        int g = t >> 1, i = t & 1;           // q row = 2g+i = t
        double v = fmax(fmax(red[0][g][i], red[1][g][i]),
                        fmax(red[2][g][i], red[3][g][i]));
        out[t] = v;
    }
}

// ---------------------------------------------------------------------------
// K3b2: combine the two chunk maxes per q row (exact fmax) and reproduce the
// original 32-lane butterfly mean (shfl_xor 1,2,4,8,16, then *1/32).
// ---------------------------------------------------------------------------
__global__ __launch_bounds__(64) void k_combine(
    const double* __restrict__ pmax, double* __restrict__ resc)
{
    const int idx = blockIdx.x;              // b*RK + r
    const int t = threadIdx.x;
    const double* p = pmax + (size_t)idx * 2 * QL;
    if (t < 32) {
        double v = fmax(p[t], p[QL + t]);
        v += __shfl_xor(v, 1);
        v += __shfl_xor(v, 2);
        v += __shfl_xor(v, 4);
        v += __shfl_xor(v, 8);
        v += __shfl_xor(v, 16);
        if (t == 0) resc[idx] = v * (1.0 / 32.0);
    }
}

// ---------------------------------------------------------------------------
// K3c: sort the RK rescored candidates by (f64 score desc, idx asc); emit k.
// ---------------------------------------------------------------------------
__global__ __launch_bounds__(RK) void k_final(
    const double* __restrict__ resc, const int* __restrict__ sel,
    const int* __restrict__ pids, float* __restrict__ out, int k)
{
    const int b = blockIdx.x;
    const int t = threadIdx.x;
    __shared__ double ss[RK];
    __shared__ int    sn[RK];

    ss[t] = resc[b * RK + t];
    sn[t] = sel[b * RK + t];
    __syncthreads();

    for (int k2 = 2; k2 <= RK; k2 <<= 1) {
        for (int j = k2 >> 1; j > 0; j >>= 1) {
            int ixj = t ^ j;
            if (ixj > t) {
                double as = ss[t], bs = ss[ixj];
                int    ai = sn[t], bi = sn[ixj];
                bool a_first = (as > bs) || (as == bs && ai < bi);
                bool desc = ((t & k2) == 0);
                if (desc ? !a_first : a_first) { ss[t] = bs; sn[t] = bi; ss[ixj] = as; sn[ixj] = ai; }
            }
            __syncthreads();
        }
    }

    if (t < k) {
        out[b * k + t]          = (float)pids[b * NC + sn[t]];  // top_pids
        out[BB * k + b * k + t] = (float)ss[t];                 // top_scores
    }
}

// ---------------------------------------------------------------------------
extern "C" void kernel_launch(void* const* d_in, const int* in_sizes, int n_in,
                              void* d_out, int out_size, void* d_ws, size_t ws_size,
                              hipStream_t stream)
{
    const float* q_vectors = (const float*)d_in[0];   // [16][32][128] f32
    const int*   topk_idx  = (const int*)d_in[1];     // [16][1024] i32
    const float* vectors   = (const float*)d_in[2];   // [20000][64][128] f32
    const int*   emb2pid   = (const int*)d_in[3];     // [1280000] i32

    const int n_emb  = in_sizes[3];
    const int n_docs = in_sizes[2] / (DLN * HD);
    const int k      = out_size / (2 * BB);           // 100

    char* ws = (char*)d_ws;
    int*    pids_ws   = (int*)ws;      ws += BB * NC * sizeof(int);        // 64 KB
    float*  scores_ws = (float*)ws;    ws += BB * NC * sizeof(float);      // 64 KB
    int*    sel_ws    = (int*)ws;      ws += BB * RK * sizeof(int);        // 8 KB
    double* resc_ws   = (double*)ws;   ws += BB * RK * sizeof(double);     // 16 KB
    double* pmax_ws   = (double*)ws;   ws += (size_t)BB * RK * 2 * QL * 8; // 1 MB
    unsigned short* qhi_ws = (unsigned short*)ws;                          // 128 KB

    k_gather_sort_dedup<<<dim3(BB), dim3(NC), 0, stream>>>(
        topk_idx, emb2pid, q_vectors, qhi_ws, n_emb, n_docs, pids_ws);

    k_screen_mfma<<<dim3(BB * NC / (4 * NPW)), dim3(256), 0, stream>>>(
        qhi_ws, vectors, pids_ws, scores_ws);

    k_select<<<dim3(BB), dim3(NC), 0, stream>>>(scores_ws, sel_ws);

    k_rescore_chunk<<<dim3(RK, 2, BB), dim3(256), 0, stream>>>(
        q_vectors, vectors, pids_ws, sel_ws, pmax_ws);

    k_combine<<<dim3(BB * RK), dim3(64), 0, stream>>>(pmax_ws, resc_ws);

    k_final<<<dim3(BB), dim3(RK), 0, stream>>>(
        resc_ws, sel_ws, pids_ws, (float*)d_out, k);
}

// Round 9
// 167.613 us; speedup vs baseline: 1.4696x; 1.4696x over previous
//
#include <hip/hip_runtime.h>
#include <hip/hip_bf16.h>
#include <math.h>

#define BB   16      // batch
#define NC   1024    // candidates per query row
#define QL   32      // query tokens
#define HD   128     // embed dim
#define DLN  64      // doc tokens per doc
#define RK   128     // rescore set size per row (pow2, >= k=100 with margin)
#define NPW  2       // candidates per wave in the screen kernel

typedef __attribute__((ext_vector_type(8))) short bf16x8;   // 8 bf16 (4 VGPRs)
typedef __attribute__((ext_vector_type(4))) float f32x4;    // MFMA accumulator
typedef __attribute__((ext_vector_type(4))) double f64x4;   // f64 MFMA accum

// ---------------------------------------------------------------------------
// K0: precompute bf16(q) for the MFMA screen.
// ---------------------------------------------------------------------------
__global__ __launch_bounds__(256) void k_qprep(
    const float* __restrict__ q, unsigned short* __restrict__ qhi)
{
    int i = blockIdx.x * 256 + threadIdx.x;          // BB*QL*HD = 65536
    float v = q[i];
    __hip_bfloat16 h = __float2bfloat16(v);
    qhi[i] = *reinterpret_cast<unsigned short*>(&h);
}

// ---------------------------------------------------------------------------
// K1: pids = emb2pid[topk]; validate; per-row descending bitonic sort; dedup.
// ---------------------------------------------------------------------------
__global__ __launch_bounds__(1024) void k_gather_sort_dedup(
    const int* __restrict__ topk, const int* __restrict__ emb2pid,
    int n_emb, int n_docs, int* __restrict__ pids_out)
{
    const int b = blockIdx.x;
    const int t = threadIdx.x;
    __shared__ int s[NC];

    int idx = topk[b * NC + t];
    int pid = (idx >= 0 && idx < n_emb) ? emb2pid[idx] : -1;
    if (pid < 0 || pid >= n_docs) pid = -1;
    s[t] = pid;
    __syncthreads();

    for (int k2 = 2; k2 <= NC; k2 <<= 1) {
        for (int j = k2 >> 1; j > 0; j >>= 1) {
            int ixj = t ^ j;
            if (ixj > t) {
                int a = s[t], c = s[ixj];
                bool desc = ((t & k2) == 0);
                if (desc ? (a < c) : (a > c)) { s[t] = c; s[ixj] = a; }
            }
            __syncthreads();
        }
    }
    int v = s[t];
    pids_out[b * NC + t] = (t > 0 && v == s[t - 1]) ? -1 : v;
}

// ---------------------------------------------------------------------------
// Round 8 f32 to bf16 (RNE) -> one bf16x8 fragment.
// ---------------------------------------------------------------------------
__device__ __forceinline__ bf16x8 cvt8(float4 a, float4 c)
{
    float v[8] = {a.x, a.y, a.z, a.w, c.x, c.y, c.z, c.w};
    bf16x8 r;
#pragma unroll
    for (int j = 0; j < 8; ++j) {
        __hip_bfloat16 h = __float2bfloat16(v[j]);
        r[j] = *reinterpret_cast<short*>(&h);
    }
    return r;
}

// ---------------------------------------------------------------------------
// K2: MFMA screening (R7 version, kept). One wave per NPW cands; register-
// direct doc loads, no LDS/barriers; launch_bounds(256,4) caps VGPR at 128.
// ---------------------------------------------------------------------------
__global__ __launch_bounds__(256, 4) void k_screen_mfma(
    const unsigned short* __restrict__ qhi,  // [BB][QL][HD] bf16(q)
    const float* __restrict__ vecs,          // [n_docs][DLN][HD] f32
    const int* __restrict__ pids,            // [BB][NC]
    float* __restrict__ scores)              // [BB][NC]
{
    const int lane = threadIdx.x & 63;
    const int wv   = threadIdx.x >> 6;              // 0..3
    const int bk   = blockIdx.x;
    const int BPR  = NC / (4 * NPW);                // blocks per batch row
    const int b    = bk / BPR;
    const int nb   = (bk % BPR) * (4 * NPW) + wv * NPW;

    const int r16 = lane & 15;
    const int kb  = lane >> 4;

    bf16x8 qf[2][4];
#pragma unroll
    for (int m = 0; m < 2; ++m)
#pragma unroll
        for (int ks = 0; ks < 4; ++ks) {
            int off = ((b * QL + m * 16 + r16) * HD + ks * 32 + kb * 8);
            qf[m][ks] = *(const bf16x8*)(qhi + off);
        }

    for (int nn = 0; nn < NPW; ++nn) {
        const int n = nb + nn;
        const int pid = pids[b * NC + n];
        if (pid < 0) {
            if (lane == 0) scores[b * NC + n] = -__builtin_inff();
            continue;
        }
        const float* dbase = vecs + (size_t)pid * (DLN * HD);

        f32x4 acc[2][4] = {};
#pragma unroll
        for (int ks = 0; ks < 4; ++ks) {
#pragma unroll
            for (int nt = 0; nt < 4; ++nt) {
                const float* p = dbase + (nt * 16 + r16) * HD + ks * 32 + kb * 8;
                float4 x0 = *(const float4*)p;
                float4 x1 = *(const float4*)(p + 4);
                bf16x8 bh = cvt8(x0, x1);
#pragma unroll
                for (int m = 0; m < 2; ++m)
                    acc[m][nt] = __builtin_amdgcn_mfma_f32_16x16x32_bf16(
                        qf[m][ks], bh, acc[m][nt], 0, 0, 0);
            }
        }

        float s = 0.f;
#pragma unroll
        for (int m = 0; m < 2; ++m) {
#pragma unroll
            for (int r = 0; r < 4; ++r) {
                float x = fmaxf(fmaxf(acc[m][0][r], acc[m][1][r]),
                                fmaxf(acc[m][2][r], acc[m][3][r]));
                x = fmaxf(x, __shfl_xor(x, 1));
                x = fmaxf(x, __shfl_xor(x, 2));
                x = fmaxf(x, __shfl_xor(x, 4));
                x = fmaxf(x, __shfl_xor(x, 8));
                s += x;
            }
        }
        s += __shfl_xor(s, 16);
        s += __shfl_xor(s, 32);
        if (lane == 0) scores[b * NC + n] = s * (1.0f / 32.0f);
    }
}

// ---------------------------------------------------------------------------
// K3a: per-row full bitonic sort of (f32 score desc, idx asc); keep top RK.
// ---------------------------------------------------------------------------
__global__ __launch_bounds__(1024) void k_select(
    const float* __restrict__ scores, int* __restrict__ sel)
{
    const int b = blockIdx.x;
    const int t = threadIdx.x;
    __shared__ float ss[NC];
    __shared__ int   si[NC];

    ss[t] = scores[b * NC + t];
    si[t] = t;
    __syncthreads();

    for (int k2 = 2; k2 <= NC; k2 <<= 1) {
        for (int j = k2 >> 1; j > 0; j >>= 1) {
            int ixj = t ^ j;
            if (ixj > t) {
                float as = ss[t], bs = ss[ixj];
                int   ai = si[t], bi = si[ixj];
                bool a_first = (as > bs) || (as == bs && ai < bi);
                bool desc = ((t & k2) == 0);
                if (desc ? !a_first : a_first) { ss[t] = bs; si[t] = bi; ss[ixj] = as; si[ixj] = ai; }
            }
            __syncthreads();
        }
    }
    if (t < RK) sel[b * RK + t] = si[t];
}

// ---------------------------------------------------------------------------
// K3b: f64-MFMA rescore of the RK selected per row. One block per candidate:
// stage q (32x128) and doc (64x128) f32 tiles in LDS (+4 pad -> <=2-way bank
// aliasing on the scalar fragment reads = free). Wave wv owns doc quarter
// nt=wv and computes S[32q][16d] over K=128 via v_mfma_f64_16x16x4_f64:
//   A frag: lane = q  [m*16 + (l&15)][ks*4 + (l>>4)]   (A[row][k])
//   B frag: lane = doc[wv*16 + (l&15)][ks*4 + (l>>4)]  (B[k][col], doc^T)
//   C/D:    col = l&15 (doc), row = (l>>4)*4 + reg (q) — 16x16 family layout
// f64 error ~1e-12 vs np order: identical ranks; f32-cast scores <=1 ulp off.
// ---------------------------------------------------------------------------
#define DPAD (HD + 4)   // 132: float4-aligned, <=2-way LDS bank aliasing

__global__ __launch_bounds__(256) void k_rescore_mfma(
    const float* __restrict__ q,     // [BB][QL][HD]
    const float* __restrict__ vecs,  // [n_docs][DLN][HD]
    const int* __restrict__ pids,    // [BB][NC]
    const int* __restrict__ sel,     // [BB][RK]
    double* __restrict__ resc)       // [BB][RK]
{
    const int r = blockIdx.x, b = blockIdx.y;
    const int t = threadIdx.x;
    const int n = sel[b * RK + r];
    const int pid = pids[b * NC + n];
    if (pid < 0) {
        if (t == 0) resc[b * RK + r] = -__builtin_inf();
        return;
    }

    __shared__ float  sq[QL][DPAD];      // 16.9 KB
    __shared__ float  sdoc[DLN][DPAD];   // 33.8 KB
    __shared__ double red[4][QL];        // 1 KB

    // Stage q tile (coalesced float4).
    {
        const float4* src = (const float4*)(q + (size_t)b * QL * HD);
        for (int i = t; i < QL * HD / 4; i += 256) {
            int row = i >> 5, c4 = (i & 31) << 2;
            *(float4*)&sq[row][c4] = src[i];
        }
    }
    // Stage doc tile.
    {
        const float4* src = (const float4*)(vecs + (size_t)pid * DLN * HD);
        for (int i = t; i < DLN * HD / 4; i += 256) {
            int row = i >> 5, c4 = (i & 31) << 2;
            *(float4*)&sdoc[row][c4] = src[i];
        }
    }
    __syncthreads();

    const int lane = t & 63;
    const int wv   = t >> 6;             // doc-column quarter
    const int c16  = lane & 15;
    const int kq   = lane >> 4;          // k within the K=4 step

    f64x4 acc[2] = {};
#pragma unroll 4
    for (int ks = 0; ks < 32; ++ks) {
        double bv = (double)sdoc[wv * 16 + c16][ks * 4 + kq];
        double a0 = (double)sq[c16][ks * 4 + kq];
        double a1 = (double)sq[16 + c16][ks * 4 + kq];
        acc[0] = __builtin_amdgcn_mfma_f64_16x16x4f64(a0, bv, acc[0], 0, 0, 0);
        acc[1] = __builtin_amdgcn_mfma_f64_16x16x4f64(a1, bv, acc[1], 0, 0, 0);
    }

    // Row-max over this wave's 16 doc cols (lanes sharing l>>4 group).
#pragma unroll
    for (int m = 0; m < 2; ++m)
#pragma unroll
        for (int rr = 0; rr < 4; ++rr) {
            double x = acc[m][rr];
            x = fmax(x, __shfl_xor(x, 1));
            x = fmax(x, __shfl_xor(x, 2));
            x = fmax(x, __shfl_xor(x, 4));
            x = fmax(x, __shfl_xor(x, 8));
            if (c16 == 0) red[wv][m * 16 + kq * 4 + rr] = x;
        }
    __syncthreads();

    if (t < 32) {
        double v = fmax(fmax(red[0][t], red[1][t]), fmax(red[2][t], red[3][t]));
        v += __shfl_xor(v, 1);
        v += __shfl_xor(v, 2);
        v += __shfl_xor(v, 4);
        v += __shfl_xor(v, 8);
        v += __shfl_xor(v, 16);
        if (t == 0) resc[b * RK + r] = v * (1.0 / 32.0);
    }
}

// ---------------------------------------------------------------------------
// K3c: sort the RK rescored candidates by (f64 score desc, idx asc); emit k.
// ---------------------------------------------------------------------------
__global__ __launch_bounds__(RK) void k_final(
    const double* __restrict__ resc, const int* __restrict__ sel,
    const int* __restrict__ pids, float* __restrict__ out, int k)
{
    const int b = blockIdx.x;
    const int t = threadIdx.x;
    __shared__ double ss[RK];
    __shared__ int    sn[RK];

    ss[t] = resc[b * RK + t];
    sn[t] = sel[b * RK + t];
    __syncthreads();

    for (int k2 = 2; k2 <= RK; k2 <<= 1) {
        for (int j = k2 >> 1; j > 0; j >>= 1) {
            int ixj = t ^ j;
            if (ixj > t) {
                double as = ss[t], bs = ss[ixj];
                int    ai = sn[t], bi = sn[ixj];
                bool a_first = (as > bs) || (as == bs && ai < bi);
                bool desc = ((t & k2) == 0);
                if (desc ? !a_first : a_first) { ss[t] = bs; sn[t] = bi; ss[ixj] = as; sn[ixj] = ai; }
            }
            __syncthreads();
        }
    }

    if (t < k) {
        out[b * k + t]          = (float)pids[b * NC + sn[t]];  // top_pids
        out[BB * k + b * k + t] = (float)ss[t];                 // top_scores
    }
}

// ---------------------------------------------------------------------------
extern "C" void kernel_launch(void* const* d_in, const int* in_sizes, int n_in,
                              void* d_out, int out_size, void* d_ws, size_t ws_size,
                              hipStream_t stream)
{
    const float* q_vectors = (const float*)d_in[0];   // [16][32][128] f32
    const int*   topk_idx  = (const int*)d_in[1];     // [16][1024] i32
    const float* vectors   = (const float*)d_in[2];   // [20000][64][128] f32
    const int*   emb2pid   = (const int*)d_in[3];     // [1280000] i32

    const int n_emb  = in_sizes[3];
    const int n_docs = in_sizes[2] / (DLN * HD);
    const int k      = out_size / (2 * BB);           // 100

    char* ws = (char*)d_ws;
    int*    pids_ws   = (int*)ws;      ws += BB * NC * sizeof(int);      // 64 KB
    float*  scores_ws = (float*)ws;    ws += BB * NC * sizeof(float);    // 64 KB
    int*    sel_ws    = (int*)ws;      ws += BB * RK * sizeof(int);      // 8 KB
    double* resc_ws   = (double*)ws;   ws += BB * RK * sizeof(double);   // 16 KB
    unsigned short* qhi_ws = (unsigned short*)ws;                        // 128 KB

    k_qprep<<<dim3(BB * QL * HD / 256), dim3(256), 0, stream>>>(
        q_vectors, qhi_ws);

    k_gather_sort_dedup<<<dim3(BB), dim3(NC), 0, stream>>>(
        topk_idx, emb2pid, n_emb, n_docs, pids_ws);

    k_screen_mfma<<<dim3(BB * NC / (4 * NPW)), dim3(256), 0, stream>>>(
        qhi_ws, vectors, pids_ws, scores_ws);

    k_select<<<dim3(BB), dim3(NC), 0, stream>>>(scores_ws, sel_ws);

    k_rescore_mfma<<<dim3(RK, BB), dim3(256), 0, stream>>>(
        q_vectors, vectors, pids_ws, sel_ws, resc_ws);

    k_final<<<dim3(BB), dim3(RK), 0, stream>>>(
        resc_ws, sel_ws, pids_ws, (float*)d_out, k);
}